// Round 2
// 117.037 us; speedup vs baseline: 1.2359x; 1.2359x over previous
//
#include <hip/hip_runtime.h>

// Problem constants (inputs: (32,64,32,32) fp32; embed: (64,1024) fp32)
#define N_PIX  32768   // B*H*W
#define C_DIM  64
#define K_EMB  1024
#define HW     1024    // H*W
#define PIXB   64      // pixels per block

// d_out layout (float32, concatenated in return order):
//   quantized_out (B,C,H,W) | loss | encoding_indices | perplexity
#define OUT_Q_OFF    0
#define OUT_LOSS_OFF 2097152
#define OUT_IDX_OFF  2097153
#define OUT_PERP_OFF 2129921

typedef __attribute__((ext_vector_type(8)))  __bf16 bf16x8;
typedef __attribute__((ext_vector_type(16))) float  f32x16;

// Module-scope device buffers (no ws-size assumptions, graph-capture safe).
// g_esplit: bf16x3 split of embed, A-fragment-packed:
//   [j][tile(32 codes)][s(k/16)][h(k8 half)][c32][e(8)]  -> 3*65536 shorts = 384 KB
__device__ unsigned short g_esplit[3 * K_EMB * C_DIM];
__device__ float          g_ee[K_EMB];      // ||e_k||^2, fp32 fmaf chain (c-order)
__device__ unsigned int   g_counts[K_EMB];
__device__ float          g_lossAcc;

__device__ __forceinline__ unsigned short f2bf(float f) {   // RNE f32->bf16
    unsigned u = __float_as_uint(f);
    unsigned r = u + 0x7FFFu + ((u >> 16) & 1u);
    return (unsigned short)(r >> 16);
}
__device__ __forceinline__ float bf2f(unsigned short b) {
    return __uint_as_float(((unsigned)b) << 16);
}
__device__ __forceinline__ unsigned long long pack_score(float d, int k) {
    unsigned int u = __float_as_uint(d);
    u = (u & 0x80000000u) ? ~u : (u | 0x80000000u);  // monotone map, negative-safe
    return ((unsigned long long)u << 32) | (unsigned int)k;
}
__device__ __forceinline__ uint4 pack8(const unsigned short* v) {
    uint4 u;
    u.x = (unsigned)v[0] | ((unsigned)v[1] << 16);
    u.y = (unsigned)v[2] | ((unsigned)v[3] << 16);
    u.z = (unsigned)v[4] | ((unsigned)v[5] << 16);
    u.w = (unsigned)v[6] | ((unsigned)v[7] << 16);
    return u;
}
__device__ __forceinline__ unsigned long long shfl_xor32_u64(unsigned long long v) {
    unsigned lo = (unsigned)v, hi = (unsigned)(v >> 32);
    lo = __shfl_xor(lo, 32, 64);
    hi = __shfl_xor(hi, 32, 64);
    return ((unsigned long long)hi << 32) | lo;
}
// keep (P1 <= P2) as the two smallest seen so far
#define UPD2(P1, P2, MM) { \
    if ((MM) < P1) { P2 = P1; P1 = (MM); } else if ((MM) < P2) P2 = (MM); }
// merge sorted pair (o1<=o2) into (P1<=P2)
#define MRG2(P1, P2, O1, O2) { \
    unsigned long long _lo = (O1) < P1 ? (O1) : P1; \
    unsigned long long _hi = (O1) < P1 ? P1 : (O1); \
    unsigned long long _m2 = (O2) < P2 ? (O2) : P2; \
    P1 = _lo; P2 = _hi < _m2 ? _hi : _m2; }

// Split embed into bf16x3 A-fragment layout + ||e||^2 + zero accumulators.
__global__ void k_prep(const float* __restrict__ embed) {
    const int code = blockIdx.x * 64 + threadIdx.x;   // grid 16 x 64 -> 0..1023
    if (code == 0) g_lossAcc = 0.f;
    g_counts[code] = 0u;
    const int tile = code >> 5, c32 = code & 31;
    float ee = 0.f;
#pragma unroll 8
    for (int c = 0; c < C_DIM; ++c) {
        const float x = embed[c * K_EMB + code];      // coalesced across lanes
        ee = fmaf(x, x, ee);
        const unsigned short b1 = f2bf(x);
        const float r1 = x - bf2f(b1);
        const unsigned short b2 = f2bf(r1);
        const float r2 = r1 - bf2f(b2);
        const unsigned short b3 = f2bf(r2);
        const int s = c >> 4, hh = (c >> 3) & 1, e = c & 7;
        const int rest = ((((tile * 4 + s) * 2 + hh) * 32) + c32) * 8 + e;
        g_esplit[rest          ] = b1;
        g_esplit[rest +  65536 ] = b2;
        g_esplit[rest + 131072 ] = b3;
    }
    g_ee[code] = ee;
}

// Main: per block 64 pixels x all 1024 codes via bf16x3 MFMA distance GEMM.
// MFMA gives top-2 candidates per pixel; exact fp32 rescore (identical op
// order to the previously-verified VALU kernel) makes the final argmin.
__global__ __launch_bounds__(256, 2) void k_main(
    const float* __restrict__ inp, const float* __restrict__ embed,
    float* __restrict__ out_q, float* __restrict__ out_idx) {

    __shared__ float x_raw[C_DIM * PIXB];          // 16 KB raw fp32 tile [c][p]
    __shared__ uint4 xfrag[3 * 4 * 2 * PIXB];      // 24 KB [j][s][h][p] -> 16B frags
    __shared__ unsigned long long red1[4][PIXB];   // per-wave top-1
    __shared__ unsigned long long red2[4][PIXB];   // per-wave top-2
    __shared__ int   ksel[PIXB];
    __shared__ float lred[4];
    __shared__ float bdist;

    const int tid = threadIdx.x;
    const int n0  = blockIdx.x * PIXB;
    const int b   = n0 >> 10;
    const int hw0 = n0 & 1023;
    const float* __restrict__ xg = inp + b * (C_DIM * HW) + hw0;

    // ---- stage 1: coalesced raw tile load -> LDS (contiguous writes)
#pragma unroll
    for (int i = 0; i < 4; ++i) {
        const int F = tid + i * 256;               // float4 index 0..1023
        const int c = F >> 4, p4 = (F & 15) << 2;
        *reinterpret_cast<float4*>(&x_raw[F << 2]) =
            *reinterpret_cast<const float4*>(xg + c * HW + p4);
    }
    __syncthreads();

    // ---- stage 2: bf16x3 split into B-fragment layout + ||x||^2 partial
    float sx2 = 0.f;
#pragma unroll
    for (int cc = 0; cc < 2; ++cc) {
        const int cid = tid + cc * 256;            // 0..511 = (s,h,p)
        const int s = cid >> 7, hh = (cid >> 6) & 1, p = cid & 63;
        unsigned short b1[8], b2[8], b3[8];
#pragma unroll
        for (int e = 0; e < 8; ++e) {
            const float x = x_raw[(s * 16 + hh * 8 + e) * PIXB + p];
            sx2 = fmaf(x, x, sx2);
            b1[e] = f2bf(x);
            const float r1 = x - bf2f(b1[e]);
            b2[e] = f2bf(r1);
            const float r2 = r1 - bf2f(b2[e]);
            b3[e] = f2bf(r2);
        }
        const int fi = (s * 2 + hh) * PIXB + p;    // within one j-plane (8*PIXB)
        xfrag[fi            ] = pack8(b1);
        xfrag[fi + 8 * PIXB ] = pack8(b2);
        xfrag[fi + 16 * PIXB] = pack8(b3);
    }
    for (int off = 32; off; off >>= 1) sx2 += __shfl_down(sx2, off, 64);
    if ((tid & 63) == 0) lred[tid >> 6] = sx2;
    __syncthreads();

    // ---- distance GEMM + running top-2
    const int w   = tid >> 6;
    const int ln  = tid & 63;
    const int c31 = ln & 31;
    const int h   = ln >> 5;
    const uint4* __restrict__ eg = reinterpret_cast<const uint4*>(g_esplit);

    unsigned long long p1a = ~0ull, p2a = ~0ull;   // pt=0 pixel top-2
    unsigned long long p1b = ~0ull, p2b = ~0ull;   // pt=1 pixel top-2

#pragma unroll 1
    for (int r = 0; r < 8; ++r) {
        const int ct = r * 4 + w;                  // code tile 0..31
        const int cb = ct * 32;

        uint4 ae[3][4];                            // A frags: e1,e2,e3 x 4 k-slices
#pragma unroll
        for (int j = 0; j < 3; ++j)
#pragma unroll
            for (int s = 0; s < 4; ++s)
                ae[j][s] = eg[(((j * 32 + ct) * 4 + s) * 2 + h) * 32 + c31];

        float eev[16];
#pragma unroll
        for (int rg = 0; rg < 16; ++rg)
            eev[rg] = g_ee[cb + (rg & 3) + 8 * (rg >> 2) + 4 * h];

#pragma unroll
        for (int pt = 0; pt < 2; ++pt) {
            const int pbase = pt * 32 + c31;
            f32x16 acc = {};
            // 6 product pairs (ja + ib <= 2), 4 k-slices each -> 24 MFMAs
#pragma unroll
            for (int ib = 0; ib < 3; ++ib) {
                uint4 bx[4];
#pragma unroll
                for (int s = 0; s < 4; ++s)
                    bx[s] = xfrag[(ib * 8 + s * 2 + h) * PIXB + pbase];
#pragma unroll
                for (int ja = 0; ja < 3 - ib; ++ja)
#pragma unroll
                    for (int s = 0; s < 4; ++s)
                        acc = __builtin_amdgcn_mfma_f32_32x32x16_bf16(
                            __builtin_bit_cast(bf16x8, ae[ja][s]),
                            __builtin_bit_cast(bf16x8, bx[s]),
                            acc, 0, 0, 0);
            }
            // fold: dist = ||e||^2 - 2*dot ; pack (dist, code); running top-2
#pragma unroll
            for (int rg = 0; rg < 16; ++rg) {
                const float dist = fmaf(-2.f, acc[rg], eev[rg]);
                const unsigned long long mm =
                    pack_score(dist, cb + (rg & 3) + 8 * (rg >> 2) + 4 * h);
                if (pt == 0) { UPD2(p1a, p2a, mm) }
                else         { UPD2(p1b, p2b, mm) }
            }
        }
    }

    // combine the two lane-halves (disjoint code rows, same pixel col)
    {
        unsigned long long o1 = shfl_xor32_u64(p1a), o2 = shfl_xor32_u64(p2a);
        MRG2(p1a, p2a, o1, o2)
        o1 = shfl_xor32_u64(p1b); o2 = shfl_xor32_u64(p2b);
        MRG2(p1b, p2b, o1, o2)
        if (ln < 32) {
            red1[w][ln] = p1a; red2[w][ln] = p2a;
            red1[w][ln + 32] = p1b; red2[w][ln + 32] = p2b;
        }
    }
    __syncthreads();

    // ---- final top-2 across 4 waves + exact fp32 rescore (old-kernel order)
    if (tid < PIXB) {
        unsigned long long M1 = red1[0][tid], M2 = red2[0][tid];
        MRG2(M1, M2, red1[1][tid], red2[1][tid])
        MRG2(M1, M2, red1[2][tid], red2[2][tid])
        MRG2(M1, M2, red1[3][tid], red2[3][tid])
        const int k1 = (int)(unsigned int)(M1 & 0xFFFFFFFFull);
        const int k2 = (int)(unsigned int)(M2 & 0xFFFFFFFFull);
        // exact fp32 rescore: dot = sequential fmaf over c; dist = fmaf(-2,dot,ee)
        float d1 = 0.f, d2 = 0.f;
        const float* xcol = x_raw + tid;
#pragma unroll 8
        for (int c = 0; c < C_DIM; ++c) {
            const float xv = xcol[c * PIXB];
            d1 = fmaf(xv, embed[c * K_EMB + k1], d1);
            d2 = fmaf(xv, embed[c * K_EMB + k2], d2);
        }
        const float dist1 = fmaf(-2.f, d1, g_ee[k1]);
        const float dist2 = fmaf(-2.f, d2, g_ee[k2]);
        const unsigned long long s1 = pack_score(dist1, k1);
        const unsigned long long s2 = pack_score(dist2, k2);
        const unsigned long long m = s1 < s2 ? s1 : s2;
        const int k = (int)(unsigned int)(m & 0xFFFFFFFFull);
        ksel[tid] = k;
        out_idx[n0 + tid] = (float)k;
        atomicAdd(g_counts + k, 1u);
        // ||x-q||^2 = ||x||^2 + dist  (loss without re-reading x)
        const unsigned int u = (unsigned int)(m >> 32);
        float dist = __uint_as_float((u & 0x80000000u) ? (u & 0x7FFFFFFFu) : ~u);
        for (int off = 32; off; off >>= 1) dist += __shfl_down(dist, off, 64);
        if (tid == 0) bdist = dist;
    }
    __syncthreads();

    // ---- quantize gather + coalesced store
    {
        const int c  = tid >> 2;
        const int p0 = (tid & 3) * 16;
        float* oq = out_q + b * (C_DIM * HW) + c * HW + hw0 + p0;
        const float* er = embed + c * K_EMB;
#pragma unroll
        for (int i = 0; i < 4; ++i) {
            float4 q;
            q.x = er[ksel[p0 + i * 4 + 0]];
            q.y = er[ksel[p0 + i * 4 + 1]];
            q.z = er[ksel[p0 + i * 4 + 2]];
            q.w = er[ksel[p0 + i * 4 + 3]];
            *reinterpret_cast<float4*>(oq + i * 4) = q;
        }
    }
    if (tid == 0)
        atomicAdd(&g_lossAcc, lred[0] + lred[1] + lred[2] + lred[3] + bdist);
}

__global__ __launch_bounds__(1024) void k_scalar(float* __restrict__ out_loss,
                                                 float* __restrict__ out_perp) {
    __shared__ float red[16];
    const int tid = threadIdx.x;  // 0..1023
    float p = (float)g_counts[tid] * (1.0f / (float)N_PIX);
    float t = p * logf(p + 1e-10f);   // p==0 -> exactly 0, matches reference
    for (int off = 32; off; off >>= 1) t += __shfl_down(t, off, 64);
    if ((tid & 63) == 0) red[tid >> 6] = t;
    __syncthreads();
    if (tid == 0) {
        float s = 0.f;
#pragma unroll
        for (int i = 0; i < 16; ++i) s += red[i];
        *out_perp = expf(-s);
        *out_loss = 0.25f * g_lossAcc * (1.0f / (float)(N_PIX * C_DIM));
    }
}

extern "C" void kernel_launch(void* const* d_in, const int* in_sizes, int n_in,
                              void* d_out, int out_size, void* d_ws, size_t ws_size,
                              hipStream_t stream) {
    const float* inp   = (const float*)d_in[0];
    const float* embed = (const float*)d_in[1];
    float* out = (float*)d_out;

    k_prep<<<dim3(16), dim3(64), 0, stream>>>(embed);
    k_main<<<dim3(N_PIX / PIXB), dim3(256), 0, stream>>>(
        inp, embed, out + OUT_Q_OFF, out + OUT_IDX_OFF);
    k_scalar<<<dim3(1), dim3(1024), 0, stream>>>(out + OUT_LOSS_OFF,
                                                 out + OUT_PERP_OFF);
}